// Round 2
// baseline (870.608 us; speedup 1.0000x reference)
//
#include <hip/hip_runtime.h>
#include <math.h>

#define NTOK 16384
#define DIM  4096
#define NEXP 64
#define BK   32
#define TOKB 256   // tokens per block == threads per block

// ---------------- Phase 1: partial logits, K-split ----------------
// One token per lane; acc[64] experts in VGPRs; W via wave-uniform scalar
// loads (SGPR operand of v_fmac); tokens staged in XOR-swizzled LDS tile.
__global__ __launch_bounds__(256, 2) void router_logits(
    const float* __restrict__ tokens,
    const float* __restrict__ W,
    float* __restrict__ partial,   // [Ks][NTOK][NEXP]
    int ksLog2)
{
  __shared__ float4 sA[2][TOKB * (BK / 4)];   // 2 x 2048 x 16B = 64 KiB

  const int tid = threadIdx.x;
  const int Ks = 1 << ksLog2;
  const int bx = blockIdx.x;
  const int s  = bx & (Ks - 1);
  const int t0 = (bx >> ksLog2) * TOKB;
  const int kslice = DIM >> ksLog2;
  const int kbase0 = s * kslice;
  const int nchunk = kslice / BK;

  // staging map: thread -> (row block, k-quad); 8 lanes cover one 128B row
  const int kq = tid & 7;
  const int rb = tid >> 3;

  float acc[NEXP];
  #pragma unroll
  for (int e = 0; e < NEXP; ++e) acc[e] = 0.f;

  float4 pf[8];

  // prologue: stage chunk 0
  #pragma unroll
  for (int i = 0; i < 8; ++i) {
    const int row = rb + 32 * i;
    pf[i] = *(const float4*)(tokens + (size_t)(t0 + row) * DIM + kbase0 + kq * 4);
  }
  #pragma unroll
  for (int i = 0; i < 8; ++i) {
    const int row = rb + 32 * i;
    sA[0][row * 8 + (kq ^ (row & 7))] = pf[i];   // XOR swizzle: conflict-free b128
  }
  __syncthreads();

  for (int c = 0; c < nchunk; ++c) {
    const int cur = c & 1;
    const bool more = (c + 1 < nchunk);
    if (more) {
      const int kb = kbase0 + (c + 1) * BK;
      #pragma unroll
      for (int i = 0; i < 8; ++i) {
        const int row = rb + 32 * i;
        pf[i] = *(const float4*)(tokens + (size_t)(t0 + row) * DIM + kb + kq * 4);
      }
    }

    // my token's 32 k-values -> registers (conflict-free swizzled b128 reads)
    float a[BK];
    #pragma unroll
    for (int q = 0; q < 8; ++q) {
      const float4 v = sA[cur][tid * 8 + (q ^ (tid & 7))];
      a[q*4+0] = v.x; a[q*4+1] = v.y; a[q*4+2] = v.z; a[q*4+3] = v.w;
    }

    // rank-BK update: W row slices are wave-uniform -> scalar loads
    const float* __restrict__ wbase = W + kbase0 + c * BK;
    #pragma unroll
    for (int e = 0; e < NEXP; ++e) {
      const float* __restrict__ w = wbase + (size_t)e * DIM;
      #pragma unroll
      for (int kk = 0; kk < BK; ++kk)
        acc[e] = fmaf(w[kk], a[kk], acc[e]);
    }

    if (more) {
      const int nxt = cur ^ 1;
      #pragma unroll
      for (int i = 0; i < 8; ++i) {
        const int row = rb + 32 * i;
        sA[nxt][row * 8 + (kq ^ (row & 7))] = pf[i];
      }
    }
    __syncthreads();
  }

  // write partial logits: per-lane contiguous 256B, wave-contiguous 16KB
  float* P = partial + ((size_t)s * NTOK + t0 + tid) * NEXP;
  #pragma unroll
  for (int e = 0; e < NEXP; e += 4) {
    float4 v; v.x = acc[e]; v.y = acc[e+1]; v.z = acc[e+2]; v.w = acc[e+3];
    *(float4*)(P + e) = v;
  }
}

// ---------------- Phase 2: reduce partials, softmax + top-2 ----------------
__global__ __launch_bounds__(64) void router_finish(
    const float* __restrict__ partial,
    float* __restrict__ out,
    int ksLog2)
{
  const int Ks = 1 << ksLog2;
  const int t = blockIdx.x * 64 + threadIdx.x;

  float l[NEXP];
  const float* p0 = partial + (size_t)t * NEXP;
  #pragma unroll
  for (int q = 0; q < 16; ++q) {
    const float4 v = *(const float4*)(p0 + q * 4);
    l[q*4+0] = v.x; l[q*4+1] = v.y; l[q*4+2] = v.z; l[q*4+3] = v.w;
  }
  for (int s = 1; s < Ks; ++s) {
    const float* p = partial + ((size_t)s * NTOK + t) * NEXP;
    #pragma unroll
    for (int q = 0; q < 16; ++q) {
      const float4 v = *(const float4*)(p + q * 4);
      l[q*4+0] += v.x; l[q*4+1] += v.y; l[q*4+2] += v.z; l[q*4+3] += v.w;
    }
  }

  // top-2 with lax.top_k tie-break (strict >, ascending scan keeps lower idx)
  float t1v = l[0]; int t1i = 0;
  float t2v = -INFINITY; int t2i = NEXP;
  #pragma unroll
  for (int e = 1; e < NEXP; ++e) {
    const float v = l[e];
    if (v > t1v) { t2v = t1v; t2i = t1i; t1v = v; t1i = e; }
    else if (v > t2v) { t2v = v; t2i = e; }
  }

  float ssum = 0.f;
  #pragma unroll
  for (int e = 0; e < NEXP; ++e) ssum += expf(l[e] - t1v);

  const float inv = 1.0f / ssum;
  out[t * 2 + 0] = inv;                       // exp(0)/denominator
  out[t * 2 + 1] = expf(t2v - t1v) * inv;
  out[2 * NTOK + t * 2 + 0] = (float)t1i;     // indices as float
  out[2 * NTOK + t * 2 + 1] = (float)t2i;
}

extern "C" void kernel_launch(void* const* d_in, const int* in_sizes, int n_in,
                              void* d_out, int out_size, void* d_ws, size_t ws_size,
                              hipStream_t stream) {
  const float* tokens = (const float*)d_in[0];
  const float* W      = (const float*)d_in[1];
  float* out          = (float*)d_out;
  float* partial      = (float*)d_ws;

  // adaptive K-split: largest Ks in {8,4,2,1} whose partial buffer fits d_ws
  int ksLog2 = 3;
  while (ksLog2 > 0 && (((size_t)NTOK * NEXP * 4) << ksLog2) > ws_size) --ksLog2;

  router_logits<<<(NTOK / TOKB) << ksLog2, TOKB, 0, stream>>>(tokens, W, partial, ksLog2);
  router_finish<<<NTOK / 64, 64, 0, stream>>>(partial, out, ksLog2);
}

// Round 3
// 261.687 us; speedup vs baseline: 3.3269x; 3.3269x over previous
//
#include <hip/hip_runtime.h>
#include <math.h>

#define NTOK 16384
#define DIM  4096
#define NEXP 64
#define BM   64            // tokens per block (4 waves x 16 rows)
#define NCH  (DIM / 32)    // 128 k-chunks of 32

typedef short bf16x8 __attribute__((ext_vector_type(8)));
typedef float f32x4  __attribute__((ext_vector_type(4)));

__device__ __forceinline__ unsigned short bf16_rne(float f) {
  unsigned u = __builtin_bit_cast(unsigned, f);
  u += 0x7fffu + ((u >> 16) & 1u);
  return (unsigned short)(u >> 16);
}
__device__ __forceinline__ float bf16_tof(unsigned short h) {
  unsigned u = ((unsigned)h) << 16;
  return __builtin_bit_cast(float, u);
}
__device__ __forceinline__ bool better(float v, int i, float wv, int wi) {
  return (v > wv) || (v == wv && i < wi);
}

// ---- prep: split W (fp32) into 3 stacked bf16 planes in workspace ----
__global__ __launch_bounds__(256) void split_w(
    const float* __restrict__ W,
    unsigned short* __restrict__ Wh,
    unsigned short* __restrict__ Wm,
    unsigned short* __restrict__ Wl)
{
  const int i = blockIdx.x * 256 + threadIdx.x;   // grid covers 64*4096 exactly
  const float w = W[i];
  const unsigned short h = bf16_rne(w);
  const float r1 = w - bf16_tof(h);
  const unsigned short m = bf16_rne(r1);
  const float r2 = r1 - bf16_tof(m);
  const unsigned short l = bf16_rne(r2);
  Wh[i] = h; Wm[i] = m; Wl[i] = l;
}

// ---- main: logits via 6-pass split-bf16 MFMA, fused softmax+top2 ----
__global__ __launch_bounds__(256, 2) void router_mfma(
    const float* __restrict__ tokens,
    const unsigned short* __restrict__ Wh,
    const unsigned short* __restrict__ Wm,
    const unsigned short* __restrict__ Wl,
    float* __restrict__ out)
{
  const int tid  = threadIdx.x;
  const int wid  = tid >> 6;
  const int lane = tid & 63;
  const int rc   = lane & 15;   // A-row / B-col / D-col within 16
  const int q    = lane >> 4;   // k-group
  const int rowbase = blockIdx.x * BM + wid * 16;

  // per-lane A stream: row (rowbase+rc), k = 32c + 8q + {0..7}
  const float4* ap4 = (const float4*)(tokens + (size_t)(rowbase + rc) * DIM + q * 8);

  // B pointers per expert tile and split plane; chunk c lives at index 4c
  const bf16x8* bpH[4]; const bf16x8* bpM[4]; const bf16x8* bpL[4];
  #pragma unroll
  for (int t = 0; t < 4; ++t) {
    const size_t off = (size_t)(t * 16 + rc) * DIM + q * 8;
    bpH[t] = (const bf16x8*)(Wh + off);
    bpM[t] = (const bf16x8*)(Wm + off);
    bpL[t] = (const bf16x8*)(Wl + off);
  }

  f32x4 accM[4], accS[4];
  #pragma unroll
  for (int t = 0; t < 4; ++t) {
    accM[t] = (f32x4){0.f, 0.f, 0.f, 0.f};
    accS[t] = (f32x4){0.f, 0.f, 0.f, 0.f};
  }

  auto chunk_body = [&](int c, float4 ca, float4 cb) {
    // split A into 3 bf16 fragments (consistent slot->k map with B)
    const float af[8] = {ca.x, ca.y, ca.z, ca.w, cb.x, cb.y, cb.z, cb.w};
    bf16x8 Ah, Am, Al;
    #pragma unroll
    for (int j = 0; j < 8; ++j) {
      const float a = af[j];
      const unsigned short h = bf16_rne(a);
      const float rm = a - bf16_tof(h);
      const unsigned short m = bf16_rne(rm);
      const float rl = rm - bf16_tof(m);
      Ah[j] = (short)h; Am[j] = (short)m; Al[j] = (short)bf16_rne(rl);
    }
    // B fragments for the 4 expert tiles (L2-resident)
    bf16x8 BH[4], BMv[4], BL[4];
    #pragma unroll
    for (int t = 0; t < 4; ++t) {
      BH[t]  = bpH[t][4 * c];
      BMv[t] = bpM[t][4 * c];
      BL[t]  = bpL[t][4 * c];
    }
    #pragma unroll
    for (int t = 0; t < 4; ++t) {
      accM[t] = __builtin_amdgcn_mfma_f32_16x16x32_bf16(Ah, BH[t],  accM[t], 0, 0, 0);
      accS[t] = __builtin_amdgcn_mfma_f32_16x16x32_bf16(Ah, BMv[t], accS[t], 0, 0, 0);
      accS[t] = __builtin_amdgcn_mfma_f32_16x16x32_bf16(Am, BH[t],  accS[t], 0, 0, 0);
      accS[t] = __builtin_amdgcn_mfma_f32_16x16x32_bf16(Ah, BL[t],  accS[t], 0, 0, 0);
      accS[t] = __builtin_amdgcn_mfma_f32_16x16x32_bf16(Am, BMv[t], accS[t], 0, 0, 0);
      accS[t] = __builtin_amdgcn_mfma_f32_16x16x32_bf16(Al, BH[t],  accS[t], 0, 0, 0);
    }
  };

  // 2-deep A prefetch, chunk loop unrolled x2 (static buffer names, no scratch)
  float4 pf0a = ap4[0], pf0b = ap4[1];
  float4 pf1a = ap4[8], pf1b = ap4[9];
  for (int cc = 0; cc < NCH / 2; ++cc) {
    const int c0 = 2 * cc, c1 = 2 * cc + 1;
    float4 ca = pf0a, cb = pf0b;
    if (cc < NCH / 2 - 1) { pf0a = ap4[8 * (c0 + 2)]; pf0b = ap4[8 * (c0 + 2) + 1]; }
    chunk_body(c0, ca, cb);
    ca = pf1a; cb = pf1b;
    if (cc < NCH / 2 - 1) { pf1a = ap4[8 * (c1 + 2)]; pf1b = ap4[8 * (c1 + 2) + 1]; }
    chunk_body(c1, ca, cb);
  }

  // ---- epilogue: D row = q*4+rr (token), D col = rc + 16t (expert) ----
  #pragma unroll
  for (int rr = 0; rr < 4; ++rr) {
    float v[4];
    #pragma unroll
    for (int t = 0; t < 4; ++t) v[t] = accM[t][rr] + accS[t][rr];

    float t1v = v[0]; int t1i = rc;           // expert 0*16 + rc
    float t2v = -INFINITY; int t2i = NEXP;
    #pragma unroll
    for (int t = 1; t < 4; ++t) {
      const int e = 16 * t + rc;
      if (better(v[t], e, t1v, t1i)) { t2v = t1v; t2i = t1i; t1v = v[t]; t1i = e; }
      else if (better(v[t], e, t2v, t2i)) { t2v = v[t]; t2i = e; }
    }
    #pragma unroll
    for (int mask = 1; mask < 16; mask <<= 1) {
      const float o1v = __shfl_xor(t1v, mask, 16);
      const int   o1i = __shfl_xor(t1i, mask, 16);
      const float o2v = __shfl_xor(t2v, mask, 16);
      const int   o2i = __shfl_xor(t2i, mask, 16);
      if (better(o1v, o1i, t1v, t1i)) {
        if (better(t1v, t1i, o2v, o2i)) { t2v = t1v; t2i = t1i; }
        else                            { t2v = o2v; t2i = o2i; }
        t1v = o1v; t1i = o1i;
      } else {
        if (better(o1v, o1i, t2v, t2i)) { t2v = o1v; t2i = o1i; }
      }
    }
    const float M = t1v;
    float s = 0.f;
    #pragma unroll
    for (int t = 0; t < 4; ++t) s += expf(v[t] - M);
    #pragma unroll
    for (int mask = 1; mask < 16; mask <<= 1) s += __shfl_xor(s, mask, 16);

    if (rc == 0) {
      const int tok = rowbase + q * 4 + rr;
      const float inv = 1.0f / s;
      out[tok * 2 + 0] = inv;
      out[tok * 2 + 1] = expf(t2v - M) * inv;
      out[2 * NTOK + tok * 2 + 0] = (float)t1i;
      out[2 * NTOK + tok * 2 + 1] = (float)t2i;
    }
  }
}

extern "C" void kernel_launch(void* const* d_in, const int* in_sizes, int n_in,
                              void* d_out, int out_size, void* d_ws, size_t ws_size,
                              hipStream_t stream) {
  const float* tokens = (const float*)d_in[0];
  const float* W      = (const float*)d_in[1];
  float* out          = (float*)d_out;

  unsigned short* Wh = (unsigned short*)d_ws;
  unsigned short* Wm = Wh + (size_t)NEXP * DIM;
  unsigned short* Wl = Wm + (size_t)NEXP * DIM;

  split_w<<<(NEXP * DIM) / 256, 256, 0, stream>>>(W, Wh, Wm, Wl);
  router_mfma<<<NTOK / BM, 256, 0, stream>>>(tokens, Wh, Wm, Wl, out);
}

// Round 5
// 176.421 us; speedup vs baseline: 4.9348x; 1.4833x over previous
//
#include <hip/hip_runtime.h>
#include <math.h>

#define NTOK 16384
#define DIM  4096
#define NEXP 64
#define KS   4                // K-split factor
#define KSL  (DIM / KS)       // 1024 k per slice
#define NCH  (KSL / 32)       // 32 chunks of 32 per slice
#define BM   64               // tokens per block (4 waves x 16)

typedef __fp16 f16x8 __attribute__((ext_vector_type(8)));
typedef __fp16 f16x2 __attribute__((ext_vector_type(2)));
typedef float  f32x4 __attribute__((ext_vector_type(4)));

// ---- prep: split W (fp32) into 2 fp16 planes (RNE hi, RNE residual) ----
__global__ __launch_bounds__(256) void split_w(
    const float* __restrict__ W,
    __fp16* __restrict__ Wh,
    __fp16* __restrict__ Wl)
{
  const int i = blockIdx.x * 256 + threadIdx.x;   // grid covers 64*4096
  const float w = W[i];
  const __fp16 h = (__fp16)w;                     // RNE
  const float r = w - (float)h;                   // exact
  Wh[i] = h;
  Wl[i] = (__fp16)r;                              // RNE, residual ~2^-24|w|
}

// ---- phase 1: partial logits via 3-pass split-fp16 MFMA ----
__global__ __launch_bounds__(256, 4) void router_mfma(
    const float* __restrict__ tokens,
    const __fp16* __restrict__ Wh,
    const __fp16* __restrict__ Wl,
    float* __restrict__ partial)   // [KS][NTOK][NEXP]
{
  const int tid  = threadIdx.x;
  const int wid  = tid >> 6;
  const int lane = tid & 63;
  const int rc   = lane & 15;     // A-row / B-col within 16
  const int q    = lane >> 4;     // k-group
  const int s    = blockIdx.x & (KS - 1);
  const int rowbase = (blockIdx.x >> 2) * BM + wid * 16;
  const int kbase   = s * KSL;

  // per-lane A stream: row (rowbase+rc), k = kbase + 32c + 8q + {0..7}
  const float4* ap4 = (const float4*)(tokens + (size_t)(rowbase + rc) * DIM + kbase + q * 8);

  const f16x8* bh[4]; const f16x8* bl[4];
  #pragma unroll
  for (int t = 0; t < 4; ++t) {
    const size_t off = (size_t)(t * 16 + rc) * DIM + kbase + q * 8;
    bh[t] = (const f16x8*)(Wh + off);
    bl[t] = (const f16x8*)(Wl + off);
  }

  f32x4 accM[4], accS[4];
  #pragma unroll
  for (int t = 0; t < 4; ++t) {
    accM[t] = (f32x4){0.f, 0.f, 0.f, 0.f};
    accS[t] = (f32x4){0.f, 0.f, 0.f, 0.f};
  }

  auto body = [&](int c, float4 ca, float4 cb) {
    // A split: hi plane via pkrtz (RTZ), residual plane via pkrtz
    const f16x2 h0 = __builtin_amdgcn_cvt_pkrtz(ca.x, ca.y);
    const f16x2 h1 = __builtin_amdgcn_cvt_pkrtz(ca.z, ca.w);
    const f16x2 h2 = __builtin_amdgcn_cvt_pkrtz(cb.x, cb.y);
    const f16x2 h3 = __builtin_amdgcn_cvt_pkrtz(cb.z, cb.w);
    const f16x2 m0 = __builtin_amdgcn_cvt_pkrtz(ca.x - (float)h0[0], ca.y - (float)h0[1]);
    const f16x2 m1 = __builtin_amdgcn_cvt_pkrtz(ca.z - (float)h1[0], ca.w - (float)h1[1]);
    const f16x2 m2 = __builtin_amdgcn_cvt_pkrtz(cb.x - (float)h2[0], cb.y - (float)h2[1]);
    const f16x2 m3 = __builtin_amdgcn_cvt_pkrtz(cb.z - (float)h3[0], cb.w - (float)h3[1]);
    const f16x8 Ah = {h0[0], h0[1], h1[0], h1[1], h2[0], h2[1], h3[0], h3[1]};
    const f16x8 Am = {m0[0], m0[1], m1[0], m1[1], m2[0], m2[1], m3[0], m3[1]};
    #pragma unroll
    for (int t = 0; t < 4; ++t) {
      const f16x8 BH = bh[t][4 * c];
      const f16x8 BL = bl[t][4 * c];
      accM[t] = __builtin_amdgcn_mfma_f32_16x16x32_f16(Ah, BH, accM[t], 0, 0, 0);
      accS[t] = __builtin_amdgcn_mfma_f32_16x16x32_f16(Ah, BL, accS[t], 0, 0, 0);
      accS[t] = __builtin_amdgcn_mfma_f32_16x16x32_f16(Am, BH, accS[t], 0, 0, 0);
    }
  };

  // 4-deep prefetch, static register names
  float4 p0a = ap4[0],  p0b = ap4[1];
  float4 p1a = ap4[8],  p1b = ap4[9];
  float4 p2a = ap4[16], p2b = ap4[17];
  float4 p3a = ap4[24], p3b = ap4[25];

  for (int c = 0; c < NCH; c += 4) {
    float4 ca, cb;
    ca = p0a; cb = p0b;
    if (c + 4 < NCH) { p0a = ap4[8 * (c + 4)]; p0b = ap4[8 * (c + 4) + 1]; }
    body(c + 0, ca, cb);
    ca = p1a; cb = p1b;
    if (c + 5 < NCH) { p1a = ap4[8 * (c + 5)]; p1b = ap4[8 * (c + 5) + 1]; }
    body(c + 1, ca, cb);
    ca = p2a; cb = p2b;
    if (c + 6 < NCH) { p2a = ap4[8 * (c + 6)]; p2b = ap4[8 * (c + 6) + 1]; }
    body(c + 2, ca, cb);
    ca = p3a; cb = p3b;
    if (c + 7 < NCH) { p3a = ap4[8 * (c + 7)]; p3b = ap4[8 * (c + 7) + 1]; }
    body(c + 3, ca, cb);
  }

  // write partial logits: D row = q*4+rr (token within 16), col = 16t+rc (expert)
  float* P = partial + ((size_t)s * NTOK + rowbase) * NEXP;
  #pragma unroll
  for (int rr = 0; rr < 4; ++rr) {
    const int row = q * 4 + rr;
    #pragma unroll
    for (int t = 0; t < 4; ++t)
      P[(size_t)row * NEXP + 16 * t + rc] = accM[t][rr] + accS[t][rr];
  }
}

// ---- phase 2: reduce partials, softmax + top-2 ----
__global__ __launch_bounds__(256) void router_finish(
    const float* __restrict__ partial,
    float* __restrict__ out)
{
  const int t = blockIdx.x * 256 + threadIdx.x;

  float l[NEXP];
  const float* p0 = partial + (size_t)t * NEXP;
  #pragma unroll
  for (int qq = 0; qq < 16; ++qq) {
    const float4 v = *(const float4*)(p0 + qq * 4);
    l[qq*4+0] = v.x; l[qq*4+1] = v.y; l[qq*4+2] = v.z; l[qq*4+3] = v.w;
  }
  #pragma unroll
  for (int s = 1; s < KS; ++s) {
    const float* p = partial + ((size_t)s * NTOK + t) * NEXP;
    #pragma unroll
    for (int qq = 0; qq < 16; ++qq) {
      const float4 v = *(const float4*)(p + qq * 4);
      l[qq*4+0] += v.x; l[qq*4+1] += v.y; l[qq*4+2] += v.z; l[qq*4+3] += v.w;
    }
  }

  // top-2, lax.top_k tie-break (ascending scan with strict > keeps lower idx)
  float t1v = l[0]; int t1i = 0;
  float t2v = -INFINITY; int t2i = NEXP;
  #pragma unroll
  for (int e = 1; e < NEXP; ++e) {
    const float v = l[e];
    if (v > t1v) { t2v = t1v; t2i = t1i; t1v = v; t1i = e; }
    else if (v > t2v) { t2v = v; t2i = e; }
  }

  float ssum = 0.f;
  #pragma unroll
  for (int e = 0; e < NEXP; ++e) ssum += expf(l[e] - t1v);

  const float inv = 1.0f / ssum;
  out[t * 2 + 0] = inv;
  out[t * 2 + 1] = expf(t2v - t1v) * inv;
  out[2 * NTOK + t * 2 + 0] = (float)t1i;
  out[2 * NTOK + t * 2 + 1] = (float)t2i;
}

extern "C" void kernel_launch(void* const* d_in, const int* in_sizes, int n_in,
                              void* d_out, int out_size, void* d_ws, size_t ws_size,
                              hipStream_t stream) {
  const float* tokens = (const float*)d_in[0];
  const float* W      = (const float*)d_in[1];
  float* out          = (float*)d_out;

  __fp16* Wh = (__fp16*)d_ws;
  __fp16* Wl = Wh + (size_t)NEXP * DIM;
  float* partial = (float*)((char*)d_ws + (size_t)2 * NEXP * DIM * sizeof(__fp16));

  split_w<<<(NEXP * DIM) / 256, 256, 0, stream>>>(W, Wh, Wl);
  router_mfma<<<(NTOK / BM) * KS, 256, 0, stream>>>(tokens, Wh, Wl, partial);
  router_finish<<<NTOK / 256, 256, 0, stream>>>(partial, out);
}

// Round 6
// 166.103 us; speedup vs baseline: 5.2414x; 1.0621x over previous
//
#include <hip/hip_runtime.h>
#include <math.h>

#define NTOK 16384
#define DIM  4096
#define NEXP 64
#define KS   4                // K-split factor
#define KSL  (DIM / KS)       // 1024 k per slice
#define NCH  (KSL / 32)       // 32 chunks of 32 per slice
#define BM   64               // tokens per block (4 waves x 16)

typedef __fp16 f16x8 __attribute__((ext_vector_type(8)));
typedef __fp16 f16x2 __attribute__((ext_vector_type(2)));
typedef float  f32x4 __attribute__((ext_vector_type(4)));

// ---- prep: split W (fp32) into 2 fp16 planes (RNE hi, RNE residual) ----
__global__ __launch_bounds__(256) void split_w(
    const float* __restrict__ W,
    __fp16* __restrict__ Wh,
    __fp16* __restrict__ Wl)
{
  const int i = blockIdx.x * 256 + threadIdx.x;   // grid covers 64*4096
  const float w = W[i];
  const __fp16 h = (__fp16)w;                     // RNE
  const float r = w - (float)h;                   // exact
  Wh[i] = h;
  Wl[i] = (__fp16)r;                              // RNE, residual ~2^-24|w|
}

// ---- phase 1: partial logits via 3-pass split-fp16 MFMA ----
// Explicit SW pipeline: A 4-deep (HBM), B 2-deep parity sets P/Q (L2).
__global__ __launch_bounds__(256, 2) void router_mfma(
    const float* __restrict__ tokens,
    const __fp16* __restrict__ Wh,
    const __fp16* __restrict__ Wl,
    float* __restrict__ partial)   // [KS][NTOK][NEXP]
{
  const int tid  = threadIdx.x;
  const int wid  = tid >> 6;
  const int lane = tid & 63;
  const int rc   = lane & 15;     // A-row / B-col within 16
  const int q    = lane >> 4;     // k-group
  const int s    = blockIdx.x & (KS - 1);
  const int rowbase = (blockIdx.x >> 2) * BM + wid * 16;
  const int kbase   = s * KSL;

  // per-lane A stream: row (rowbase+rc), k = kbase + 32c + 8q + {0..7}
  const float4* ap4 = (const float4*)(tokens + (size_t)(rowbase + rc) * DIM + kbase + q * 8);

  // B pointers: expert tile t covers experts 16t..16t+15; chunk c at idx 4c
  const f16x8* bp0 = (const f16x8*)(Wh + (size_t)(0 * 16 + rc) * DIM + kbase + q * 8);
  const f16x8* bp1 = (const f16x8*)(Wh + (size_t)(1 * 16 + rc) * DIM + kbase + q * 8);
  const f16x8* bp2 = (const f16x8*)(Wh + (size_t)(2 * 16 + rc) * DIM + kbase + q * 8);
  const f16x8* bp3 = (const f16x8*)(Wh + (size_t)(3 * 16 + rc) * DIM + kbase + q * 8);
  const f16x8* lp0 = (const f16x8*)(Wl + (size_t)(0 * 16 + rc) * DIM + kbase + q * 8);
  const f16x8* lp1 = (const f16x8*)(Wl + (size_t)(1 * 16 + rc) * DIM + kbase + q * 8);
  const f16x8* lp2 = (const f16x8*)(Wl + (size_t)(2 * 16 + rc) * DIM + kbase + q * 8);
  const f16x8* lp3 = (const f16x8*)(Wl + (size_t)(3 * 16 + rc) * DIM + kbase + q * 8);

  f32x4 acc0 = {0.f,0.f,0.f,0.f}, acc1 = {0.f,0.f,0.f,0.f};
  f32x4 acc2 = {0.f,0.f,0.f,0.f}, acc3 = {0.f,0.f,0.f,0.f};

  // B pipeline registers: parity sets P (even chunks) / Q (odd chunks)
  f16x8 Ph0 = bp0[0], Ph1 = bp1[0], Ph2 = bp2[0], Ph3 = bp3[0];
  f16x8 Pl0 = lp0[0], Pl1 = lp1[0], Pl2 = lp2[0], Pl3 = lp3[0];
  f16x8 Qh0 = bp0[4], Qh1 = bp1[4], Qh2 = bp2[4], Qh3 = bp3[4];
  f16x8 Ql0 = lp0[4], Ql1 = lp1[4], Ql2 = lp2[4], Ql3 = lp3[4];

  // A pipeline registers: 4-deep
  float4 A0a = ap4[0],  A0b = ap4[1];
  float4 A1a = ap4[8],  A1b = ap4[9];
  float4 A2a = ap4[16], A2b = ap4[17];
  float4 A3a = ap4[24], A3b = ap4[25];

  // one chunk: consume (Aa,Ab) + B set, refill B set <- k+2, A set <- k+4
#define SUB(kk, Aa_, Ab_, BH0, BH1, BH2, BH3, BL0, BL1, BL2, BL3)          \
  {                                                                        \
    const f16x8 th0 = BH0, th1 = BH1, th2 = BH2, th3 = BH3;                \
    const f16x8 tl0 = BL0, tl1 = BL1, tl2 = BL2, tl3 = BL3;                \
    const float4 ca = Aa_, cb = Ab_;                                       \
    if ((kk) + 2 < NCH) {                                                  \
      BH0 = bp0[4 * ((kk) + 2)]; BH1 = bp1[4 * ((kk) + 2)];                \
      BH2 = bp2[4 * ((kk) + 2)]; BH3 = bp3[4 * ((kk) + 2)];                \
      BL0 = lp0[4 * ((kk) + 2)]; BL1 = lp1[4 * ((kk) + 2)];                \
      BL2 = lp2[4 * ((kk) + 2)]; BL3 = lp3[4 * ((kk) + 2)];                \
    }                                                                      \
    if ((kk) + 4 < NCH) {                                                  \
      Aa_ = ap4[8 * ((kk) + 4)]; Ab_ = ap4[8 * ((kk) + 4) + 1];            \
    }                                                                      \
    const f16x2 h0 = __builtin_amdgcn_cvt_pkrtz(ca.x, ca.y);               \
    const f16x2 h1 = __builtin_amdgcn_cvt_pkrtz(ca.z, ca.w);               \
    const f16x2 h2 = __builtin_amdgcn_cvt_pkrtz(cb.x, cb.y);               \
    const f16x2 h3 = __builtin_amdgcn_cvt_pkrtz(cb.z, cb.w);               \
    const f16x2 m0 = __builtin_amdgcn_cvt_pkrtz(ca.x - (float)h0[0],       \
                                                ca.y - (float)h0[1]);      \
    const f16x2 m1 = __builtin_amdgcn_cvt_pkrtz(ca.z - (float)h1[0],       \
                                                ca.w - (float)h1[1]);      \
    const f16x2 m2 = __builtin_amdgcn_cvt_pkrtz(cb.x - (float)h2[0],       \
                                                cb.y - (float)h2[1]);      \
    const f16x2 m3 = __builtin_amdgcn_cvt_pkrtz(cb.z - (float)h3[0],       \
                                                cb.w - (float)h3[1]);      \
    const f16x8 Ah = {h0[0], h0[1], h1[0], h1[1], h2[0], h2[1], h3[0], h3[1]}; \
    const f16x8 Am = {m0[0], m0[1], m1[0], m1[1], m2[0], m2[1], m3[0], m3[1]}; \
    acc0 = __builtin_amdgcn_mfma_f32_16x16x32_f16(Ah, th0, acc0, 0, 0, 0); \
    acc1 = __builtin_amdgcn_mfma_f32_16x16x32_f16(Ah, th1, acc1, 0, 0, 0); \
    acc2 = __builtin_amdgcn_mfma_f32_16x16x32_f16(Ah, th2, acc2, 0, 0, 0); \
    acc3 = __builtin_amdgcn_mfma_f32_16x16x32_f16(Ah, th3, acc3, 0, 0, 0); \
    acc0 = __builtin_amdgcn_mfma_f32_16x16x32_f16(Ah, tl0, acc0, 0, 0, 0); \
    acc1 = __builtin_amdgcn_mfma_f32_16x16x32_f16(Ah, tl1, acc1, 0, 0, 0); \
    acc2 = __builtin_amdgcn_mfma_f32_16x16x32_f16(Ah, tl2, acc2, 0, 0, 0); \
    acc3 = __builtin_amdgcn_mfma_f32_16x16x32_f16(Ah, tl3, acc3, 0, 0, 0); \
    acc0 = __builtin_amdgcn_mfma_f32_16x16x32_f16(Am, th0, acc0, 0, 0, 0); \
    acc1 = __builtin_amdgcn_mfma_f32_16x16x32_f16(Am, th1, acc1, 0, 0, 0); \
    acc2 = __builtin_amdgcn_mfma_f32_16x16x32_f16(Am, th2, acc2, 0, 0, 0); \
    acc3 = __builtin_amdgcn_mfma_f32_16x16x32_f16(Am, th3, acc3, 0, 0, 0); \
  }

  #pragma unroll
  for (int c = 0; c < NCH; c += 4) {
    SUB(c + 0, A0a, A0b, Ph0, Ph1, Ph2, Ph3, Pl0, Pl1, Pl2, Pl3);
    SUB(c + 1, A1a, A1b, Qh0, Qh1, Qh2, Qh3, Ql0, Ql1, Ql2, Ql3);
    SUB(c + 2, A2a, A2b, Ph0, Ph1, Ph2, Ph3, Pl0, Pl1, Pl2, Pl3);
    SUB(c + 3, A3a, A3b, Qh0, Qh1, Qh2, Qh3, Ql0, Ql1, Ql2, Ql3);
  }
#undef SUB

  // write partial logits: D row = q*4+rr (token within 16), col = 16t+rc
  float* P = partial + ((size_t)s * NTOK + rowbase) * NEXP;
  #pragma unroll
  for (int rr = 0; rr < 4; ++rr) {
    const int row = q * 4 + rr;
    P[(size_t)row * NEXP +  0 + rc] = acc0[rr];
    P[(size_t)row * NEXP + 16 + rc] = acc1[rr];
    P[(size_t)row * NEXP + 32 + rc] = acc2[rr];
    P[(size_t)row * NEXP + 48 + rc] = acc3[rr];
  }
}

// ---- phase 2: reduce partials, softmax + top-2 ----
__global__ __launch_bounds__(64) void router_finish(
    const float* __restrict__ partial,
    float* __restrict__ out)
{
  const int t = blockIdx.x * 64 + threadIdx.x;

  float l[NEXP];
  const float* p0 = partial + (size_t)t * NEXP;
  #pragma unroll
  for (int qq = 0; qq < 16; ++qq) {
    const float4 v = *(const float4*)(p0 + qq * 4);
    l[qq*4+0] = v.x; l[qq*4+1] = v.y; l[qq*4+2] = v.z; l[qq*4+3] = v.w;
  }
  #pragma unroll
  for (int s = 1; s < KS; ++s) {
    const float* p = partial + ((size_t)s * NTOK + t) * NEXP;
    #pragma unroll
    for (int qq = 0; qq < 16; ++qq) {
      const float4 v = *(const float4*)(p + qq * 4);
      l[qq*4+0] += v.x; l[qq*4+1] += v.y; l[qq*4+2] += v.z; l[qq*4+3] += v.w;
    }
  }

  // top-2, lax.top_k tie-break (ascending scan with strict > keeps lower idx)
  float t1v = l[0]; int t1i = 0;
  float t2v = -INFINITY; int t2i = NEXP;
  #pragma unroll
  for (int e = 1; e < NEXP; ++e) {
    const float v = l[e];
    if (v > t1v) { t2v = t1v; t2i = t1i; t1v = v; t1i = e; }
    else if (v > t2v) { t2v = v; t2i = e; }
  }

  float ssum = 0.f;
  #pragma unroll
  for (int e = 0; e < NEXP; ++e) ssum += expf(l[e] - t1v);

  const float inv = 1.0f / ssum;
  out[t * 2 + 0] = inv;
  out[t * 2 + 1] = expf(t2v - t1v) * inv;
  out[2 * NTOK + t * 2 + 0] = (float)t1i;
  out[2 * NTOK + t * 2 + 1] = (float)t2i;
}

extern "C" void kernel_launch(void* const* d_in, const int* in_sizes, int n_in,
                              void* d_out, int out_size, void* d_ws, size_t ws_size,
                              hipStream_t stream) {
  const float* tokens = (const float*)d_in[0];
  const float* W      = (const float*)d_in[1];
  float* out          = (float*)d_out;

  __fp16* Wh = (__fp16*)d_ws;
  __fp16* Wl = Wh + (size_t)NEXP * DIM;
  float* partial = (float*)((char*)d_ws + (size_t)2 * NEXP * DIM * sizeof(__fp16));

  split_w<<<(NEXP * DIM) / 256, 256, 0, stream>>>(W, Wh, Wl);
  router_mfma<<<(NTOK / BM) * KS, 256, 0, stream>>>(tokens, Wh, Wl, partial);
  router_finish<<<NTOK / 64, 64, 0, stream>>>(partial, out);
}

// Round 7
// 78.683 us; speedup vs baseline: 11.0647x; 2.1110x over previous
//
#include <hip/hip_runtime.h>
#include <math.h>

#define NTOK 16384
#define DIM  4096
#define NEXP 64
#define KS   4                // K-split factor
#define KSL  (DIM / KS)       // 1024 k per slice
#define NCH  (KSL / 32)       // 32 chunks of 32 per slice
#define BM   64               // tokens per block (4 waves x 16)

typedef __fp16 f16x8 __attribute__((ext_vector_type(8)));
typedef __fp16 f16x2 __attribute__((ext_vector_type(2)));
typedef float  f32x4 __attribute__((ext_vector_type(4)));

__device__ __forceinline__ void gl_lds16(const void* g, void* l) {
  __builtin_amdgcn_global_load_lds(
      (const __attribute__((address_space(1))) void*)g,
      (__attribute__((address_space(3))) void*)l, 16, 0, 0);
}

// ---- prep: split W (fp32) into 2 fp16 planes (RNE hi, RNE residual) ----
__global__ __launch_bounds__(256) void split_w(
    const float* __restrict__ W,
    __fp16* __restrict__ Wh,
    __fp16* __restrict__ Wl)
{
  const int i = blockIdx.x * 256 + threadIdx.x;   // grid covers 64*4096
  const float w = W[i];
  const __fp16 h = (__fp16)w;                     // RNE
  const float r = w - (float)h;                   // exact
  Wh[i] = h;
  Wl[i] = (__fp16)r;                              // RNE, residual ~2^-24|w|
}

// ---- phase 1: partial logits, m97-style global_load_lds double-buffer ----
__global__ __launch_bounds__(256, 4) void router_mfma(
    const float* __restrict__ tokens,
    const __fp16* __restrict__ Wh,
    const __fp16* __restrict__ Wl,
    float* __restrict__ partial)   // [KS][NTOK][NEXP]
{
  __shared__ float  As[2][BM * 32];     // 2 x 8 KB, row = 32 f32 (128B, 8 slots)
  __shared__ __fp16 Bh[2][NEXP * 32];   // 2 x 4 KB, row = 32 f16 (64B, 4 slots)
  __shared__ __fp16 Bl[2][NEXP * 32];

  const int tid  = threadIdx.x;
  const int wid  = tid >> 6;
  const int lane = tid & 63;
  const int rc   = lane & 15;           // A-row / B-col within 16
  const int q    = lane >> 4;           // k-group (0..3)
  const int s    = blockIdx.x & (KS - 1);
  const int rowbase = (blockIdx.x >> 2) * BM;     // block token base
  const int wrow    = rowbase + 16 * wid;         // this wave's token base
  const int kbase   = s * KSL;

  // ---- staging sources (pre-swizzled global addr, linear LDS dest: G21) ----
  // A instr i in {0,1}: token r = 16*wid + 8*i + (lane>>3), slot j = lane&7,
  // source quad = j ^ (r&7) = j ^ (lane>>3)
  const int a_tl = lane >> 3, a_j = lane & 7;
  const float* asrc0 = tokens + (size_t)(wrow + a_tl) * DIM + kbase
                       + ((a_j ^ a_tl) << 2);
  const float* asrc1 = asrc0 + (size_t)8 * DIM;
  // B plane: expert e = 16*wid + (lane>>2), slot j = lane&3, src octet = j^(e&3)
  const int b_el = lane >> 2, b_j = lane & 3;
  const size_t boff = (size_t)(16 * wid + b_el) * DIM + kbase
                      + ((b_j ^ (b_el & 3)) << 3);
  const __fp16* bsrc_h = Wh + boff;
  const __fp16* bsrc_l = Wl + boff;

#define STAGE(buf, c) {                                        \
    const int ko = (c) * 32;                                   \
    gl_lds16(asrc0 + ko,  &As[buf][(16 * wid) * 32]);          \
    gl_lds16(asrc1 + ko,  &As[buf][(16 * wid + 8) * 32]);      \
    gl_lds16(bsrc_h + ko, &Bh[buf][(16 * wid) * 32]);          \
    gl_lds16(bsrc_l + ko, &Bl[buf][(16 * wid) * 32]);          \
  }

  f32x4 acc0 = {0.f,0.f,0.f,0.f}, acc1 = {0.f,0.f,0.f,0.f};
  f32x4 acc2 = {0.f,0.f,0.f,0.f}, acc3 = {0.f,0.f,0.f,0.f};

  // read-side swizzled slots (constant per thread)
  const int sa0 = (2 * q) ^ (rc & 7), sa1 = (2 * q + 1) ^ (rc & 7);
  const int sb  = q ^ (rc & 3);
  const int arow = (16 * wid + rc) * 32;

#define COMP(buf) {                                                          \
    const float4 a0 = *(const float4*)(&As[buf][arow + sa0 * 4]);            \
    const float4 a1 = *(const float4*)(&As[buf][arow + sa1 * 4]);            \
    const f16x8 bh0 = *(const f16x8*)(&Bh[buf][( 0 + rc) * 32 + sb * 8]);    \
    const f16x8 bh1 = *(const f16x8*)(&Bh[buf][(16 + rc) * 32 + sb * 8]);    \
    const f16x8 bh2 = *(const f16x8*)(&Bh[buf][(32 + rc) * 32 + sb * 8]);    \
    const f16x8 bh3 = *(const f16x8*)(&Bh[buf][(48 + rc) * 32 + sb * 8]);    \
    const f16x8 bl0 = *(const f16x8*)(&Bl[buf][( 0 + rc) * 32 + sb * 8]);    \
    const f16x8 bl1 = *(const f16x8*)(&Bl[buf][(16 + rc) * 32 + sb * 8]);    \
    const f16x8 bl2 = *(const f16x8*)(&Bl[buf][(32 + rc) * 32 + sb * 8]);    \
    const f16x8 bl3 = *(const f16x8*)(&Bl[buf][(48 + rc) * 32 + sb * 8]);    \
    const f16x2 h0 = __builtin_amdgcn_cvt_pkrtz(a0.x, a0.y);                 \
    const f16x2 h1 = __builtin_amdgcn_cvt_pkrtz(a0.z, a0.w);                 \
    const f16x2 h2 = __builtin_amdgcn_cvt_pkrtz(a1.x, a1.y);                 \
    const f16x2 h3 = __builtin_amdgcn_cvt_pkrtz(a1.z, a1.w);                 \
    const f16x2 m0 = __builtin_amdgcn_cvt_pkrtz(a0.x - (float)h0[0],         \
                                                a0.y - (float)h0[1]);        \
    const f16x2 m1 = __builtin_amdgcn_cvt_pkrtz(a0.z - (float)h1[0],         \
                                                a0.w - (float)h1[1]);        \
    const f16x2 m2 = __builtin_amdgcn_cvt_pkrtz(a1.x - (float)h2[0],         \
                                                a1.y - (float)h2[1]);        \
    const f16x2 m3 = __builtin_amdgcn_cvt_pkrtz(a1.z - (float)h3[0],         \
                                                a1.w - (float)h3[1]);        \
    const f16x8 Ah = {h0[0],h0[1],h1[0],h1[1],h2[0],h2[1],h3[0],h3[1]};      \
    const f16x8 Am = {m0[0],m0[1],m1[0],m1[1],m2[0],m2[1],m3[0],m3[1]};      \
    acc0 = __builtin_amdgcn_mfma_f32_16x16x32_f16(Ah, bh0, acc0, 0, 0, 0);   \
    acc1 = __builtin_amdgcn_mfma_f32_16x16x32_f16(Ah, bh1, acc1, 0, 0, 0);   \
    acc2 = __builtin_amdgcn_mfma_f32_16x16x32_f16(Ah, bh2, acc2, 0, 0, 0);   \
    acc3 = __builtin_amdgcn_mfma_f32_16x16x32_f16(Ah, bh3, acc3, 0, 0, 0);   \
    acc0 = __builtin_amdgcn_mfma_f32_16x16x32_f16(Ah, bl0, acc0, 0, 0, 0);   \
    acc1 = __builtin_amdgcn_mfma_f32_16x16x32_f16(Ah, bl1, acc1, 0, 0, 0);   \
    acc2 = __builtin_amdgcn_mfma_f32_16x16x32_f16(Ah, bl2, acc2, 0, 0, 0);   \
    acc3 = __builtin_amdgcn_mfma_f32_16x16x32_f16(Ah, bl3, acc3, 0, 0, 0);   \
    acc0 = __builtin_amdgcn_mfma_f32_16x16x32_f16(Am, bh0, acc0, 0, 0, 0);   \
    acc1 = __builtin_amdgcn_mfma_f32_16x16x32_f16(Am, bh1, acc1, 0, 0, 0);   \
    acc2 = __builtin_amdgcn_mfma_f32_16x16x32_f16(Am, bh2, acc2, 0, 0, 0);   \
    acc3 = __builtin_amdgcn_mfma_f32_16x16x32_f16(Am, bh3, acc3, 0, 0, 0);   \
  }

  // prologue
  STAGE(0, 0);
  __syncthreads();

  // main loop: stage next into other buffer BEFORE computing current (T3-lite)
  for (int c = 0; c < NCH; c += 2) {
    if (c + 1 < NCH) STAGE(1, c + 1);
    COMP(0);
    __syncthreads();
    if (c + 2 < NCH) STAGE(0, c + 2);
    COMP(1);
    __syncthreads();
  }
#undef STAGE
#undef COMP

  // write partial logits: D row = q*4+rr (token within 16), col = 16t+rc
  float* P = partial + ((size_t)s * NTOK + wrow) * NEXP;
  #pragma unroll
  for (int rr = 0; rr < 4; ++rr) {
    const int row = q * 4 + rr;
    P[(size_t)row * NEXP +  0 + rc] = acc0[rr];
    P[(size_t)row * NEXP + 16 + rc] = acc1[rr];
    P[(size_t)row * NEXP + 32 + rc] = acc2[rr];
    P[(size_t)row * NEXP + 48 + rc] = acc3[rr];
  }
}

// ---- phase 2: reduce partials, softmax + top-2 ----
__global__ __launch_bounds__(64) void router_finish(
    const float* __restrict__ partial,
    float* __restrict__ out)
{
  const int t = blockIdx.x * 64 + threadIdx.x;

  float l[NEXP];
  const float* p0 = partial + (size_t)t * NEXP;
  #pragma unroll
  for (int qq = 0; qq < 16; ++qq) {
    const float4 v = *(const float4*)(p0 + qq * 4);
    l[qq*4+0] = v.x; l[qq*4+1] = v.y; l[qq*4+2] = v.z; l[qq*4+3] = v.w;
  }
  #pragma unroll
  for (int s = 1; s < KS; ++s) {
    const float* p = partial + ((size_t)s * NTOK + t) * NEXP;
    #pragma unroll
    for (int qq = 0; qq < 16; ++qq) {
      const float4 v = *(const float4*)(p + qq * 4);
      l[qq*4+0] += v.x; l[qq*4+1] += v.y; l[qq*4+2] += v.z; l[qq*4+3] += v.w;
    }
  }

  // top-2, lax.top_k tie-break (ascending scan with strict > keeps lower idx)
  float t1v = l[0]; int t1i = 0;
  float t2v = -INFINITY; int t2i = NEXP;
  #pragma unroll
  for (int e = 1; e < NEXP; ++e) {
    const float v = l[e];
    if (v > t1v) { t2v = t1v; t2i = t1i; t1v = v; t1i = e; }
    else if (v > t2v) { t2v = v; t2i = e; }
  }

  float ssum = 0.f;
  #pragma unroll
  for (int e = 0; e < NEXP; ++e) ssum += expf(l[e] - t1v);

  const float inv = 1.0f / ssum;
  out[t * 2 + 0] = inv;
  out[t * 2 + 1] = expf(t2v - t1v) * inv;
  out[2 * NTOK + t * 2 + 0] = (float)t1i;
  out[2 * NTOK + t * 2 + 1] = (float)t2i;
}

extern "C" void kernel_launch(void* const* d_in, const int* in_sizes, int n_in,
                              void* d_out, int out_size, void* d_ws, size_t ws_size,
                              hipStream_t stream) {
  const float* tokens = (const float*)d_in[0];
  const float* W      = (const float*)d_in[1];
  float* out          = (float*)d_out;

  __fp16* Wh = (__fp16*)d_ws;
  __fp16* Wl = Wh + (size_t)NEXP * DIM;
  float* partial = (float*)((char*)d_ws + (size_t)2 * NEXP * DIM * sizeof(__fp16));

  split_w<<<(NEXP * DIM) / 256, 256, 0, stream>>>(W, Wh, Wl);
  router_mfma<<<(NTOK / BM) * KS, 256, 0, stream>>>(tokens, Wh, Wl, partial);
  router_finish<<<NTOK / 64, 64, 0, stream>>>(partial, out);
}